// Round 1
// baseline (540.145 us; speedup 1.0000x reference)
//
#include <hip/hip_runtime.h>

#define EPS_BN 1e-5f

typedef __attribute__((ext_vector_type(8))) short sh8;
typedef __attribute__((ext_vector_type(4))) short sh4;
typedef __attribute__((ext_vector_type(4))) float f32x4;

// ================= fp32 workspace arena =================
static const size_t WF_OFF[5] = {0, 1944, 33048, 157464, 655128};  // fused fp32 weights [COUT][K]
static const size_t PART_OFF = 2645784;   // split-K partials (max 3*6272*192 = 3612672)
static const size_t PRE_OFF  = 6258456;   // pre-BN flat conv output (max 2408448)
static const size_t OUT5_OFF = 8666904;   // 110592 L5 pre-BN flat
static const size_t H_OFF    = 8777496;   // 110592 fc1 input (NCDHW flat)
static const size_t ST_OFF   = 8888088;   // 768 per-channel scale/shift
static const size_t BNP_OFF  = 8888856;   // 64 rows x 768 = 49152 bn atomic partials
static const size_t H1_OFF   = 8938008;   // 1024 fc1 output
static const size_t WS_TOT   = 8939032;   // ~35.8 MB
__device__ __align__(256) float g_ws[WS_TOT];

// bf16 activation arena (halo-padded NDHWC)
static const size_t XIN_OFF = 0;         // [2][18][114][114][4]  = 1871424 (fully written by convert_input)
static const size_t A1_OFF  = 1871424;   // [2][18][58][58][24]   = 2905344
static const size_t A2_OFF  = 4776768;   // [2][18][30][30][48]   = 1555200
static const size_t A3_OFF  = 6331968;   // [2][18][16][16][96]   = 884736
static const size_t A4_OFF  = 7216704;   // [2][18][9][9][192]    = 559872
static const size_t AR_TOT  = 7776576;
__device__ __align__(256) unsigned short g_act[AR_TOT];

// bf16 conv weights [NPAD][KPAD], k-order = s*CPAD+c
static const size_t WB_OFF[5] = {0, 4096, 36352, 162304, 659968};
__device__ __align__(256) unsigned short g_wb[2650624];

__device__ inline unsigned short f2bf(float v) {
    unsigned u = __float_as_uint(v);
    return (unsigned short)((u + 0x7fffu + ((u >> 16) & 1u)) >> 16);
}

// ================= zero activation arena (A1..A4 only; xin covered by convert) =================
__global__ __launch_bounds__(256) void zero16(int4* __restrict__ p, int n) {
    const int i = blockIdx.x * 256 + threadIdx.x;
    if (i < n) p[i] = make_int4(0, 0, 0, 0);
}

// ================= input: NCDHW fp32 -> halo NDHWC bf16 (Cpad=4); also zero bnp =================
__global__ __launch_bounds__(256) void convert_input(const float* __restrict__ x,
                                                     unsigned short* __restrict__ xp,
                                                     float* __restrict__ bnp)
{
    const int i = blockIdx.x * 256 + threadIdx.x;
    if (i < 49152) bnp[i] = 0.f;
    if (i >= 2 * 18 * 114 * 114 * 4) return;
    const int c = i & 3;
    int t = i >> 2;
    const int xx = t % 114; t /= 114;
    const int yy = t % 114; t /= 114;
    const int zz = t % 18;
    const int b  = t / 18;
    float v = 0.f;
    if (c < 3 && (unsigned)(zz - 1) < 16u && (unsigned)(yy - 1) < 112u && (unsigned)(xx - 1) < 112u)
        v = x[(((size_t)b * 3 + c) * 16 + (zz - 1)) * 12544 + (yy - 1) * 112 + (xx - 1)];
    xp[i] = f2bf(v);
}

// ================= fuse ALL layers in one dispatch =================
struct FuseArgs {
    const float* proj[5];
    const float* alpha[5];
    float* Wf[5];
    int K[5];
    int CO[5];
    int NT[5];
    int start[6];
};

__global__ __launch_bounds__(256) void fuse_all(FuseArgs a)
{
    __shared__ __align__(16) float sa[16][64];  // [p][o]
    __shared__ __align__(16) float sp[16][64];  // [p][k]

    int l = 0;
    {
        const int bx = blockIdx.x;
        while (l < 4 && bx >= a.start[l + 1]) ++l;
    }
    const int idx = blockIdx.x - a.start[l];
    const int NT = a.NT[l];
    const int obase = (idx / NT) * 64;
    const int kbase = (idx % NT) * 64;
    const int K = a.K[l], CO = a.CO[l];
    const float* __restrict__ proj  = a.proj[l];
    const float* __restrict__ alpha = a.alpha[l];
    float* __restrict__ Wf = a.Wf[l];

    const int tid = threadIdx.x;
    const int tk = tid & 15, to = tid >> 4;

    const int pp  = tid >> 4;
    const int col = (tid & 15) * 4;
    const int o_st = obase + col;
    const int k_st = kbase + col;
    const bool a_ok  = (o_st < CO);
    const bool p_vec = ((K & 3) == 0) && (k_st + 4 <= K);

    float acc[4][4];
    #pragma unroll
    for (int i = 0; i < 4; ++i)
        #pragma unroll
        for (int j = 0; j < 4; ++j) acc[i][j] = 0.f;

    for (int p0 = 0; p0 < 512; p0 += 16) {
        const float* ap  = alpha + (size_t)(p0 + pp) * CO;
        const float* prp = proj  + (size_t)(p0 + pp) * K;
        float4 va = make_float4(0.f, 0.f, 0.f, 0.f);
        float4 vp = make_float4(0.f, 0.f, 0.f, 0.f);
        if (a_ok) va = *(const float4*)(ap + o_st);
        if (p_vec) {
            vp = *(const float4*)(prp + k_st);
        } else {
            float t4[4];
            #pragma unroll
            for (int j = 0; j < 4; ++j)
                t4[j] = (k_st + j < K) ? prp[k_st + j] : 0.f;
            vp = make_float4(t4[0], t4[1], t4[2], t4[3]);
        }
        *(float4*)&sa[pp][col] = va;
        *(float4*)&sp[pp][col] = vp;
        __syncthreads();
        #pragma unroll
        for (int p = 0; p < 16; ++p) {
            const float4 a4 = *(const float4*)&sa[p][to * 4];
            const float4 b4 = *(const float4*)&sp[p][tk * 4];
            const float aa[4] = {a4.x, a4.y, a4.z, a4.w};
            const float bb[4] = {b4.x, b4.y, b4.z, b4.w};
            #pragma unroll
            for (int i = 0; i < 4; ++i)
                #pragma unroll
                for (int j = 0; j < 4; ++j)
                    acc[i][j] = fmaf(aa[i], bb[j], acc[i][j]);
        }
        __syncthreads();
    }

    #pragma unroll
    for (int i = 0; i < 4; ++i) {
        const int o = obase + to * 4 + i;
        if (o < CO) {
            #pragma unroll
            for (int j = 0; j < 4; ++j) {
                const int kk = kbase + tk * 4 + j;
                if (kk < K) Wf[(size_t)o * K + kk] = acc[i][j];
            }
        }
    }
}

// ================= reorder ALL layers in one dispatch =================
struct ReordArgs {
    const float* Wf[5];
    unsigned short* Wb[5];
    int K[5], CPAD[5], KPAD[5], CO[5];
    int start[6];
};

__global__ __launch_bounds__(256) void reorder_all(ReordArgs a)
{
    int l = 0;
    {
        const int bx = blockIdx.x;
        while (l < 4 && bx >= a.start[l + 1]) ++l;
    }
    const int o = blockIdx.x - a.start[l];
    const int K = a.K[l], CPAD = a.CPAD[l], KPAD = a.KPAD[l], CO = a.CO[l];
    const int tid = threadIdx.x;
    unsigned short* row = a.Wb[l] + (size_t)o * KPAD;
    for (int i = tid; i < KPAD; i += 256) row[i] = 0;
    __syncthreads();
    if (o < CO) {
        const float* wr = a.Wf[l] + (size_t)o * K;
        for (int k = tid; k < K; k += 256) {
            const int c = k / 27, s = k - c * 27;
            row[s * CPAD + c] = f2bf(wr[k]);
        }
    }
}

// ================= implicit-GEMM MFMA conv + clamp(1+x,0) + pool(1,2,2) + fused BN stats =================
// SPLIT==1: writes pre-BN fp32 flat [pooled][COUT] AND accumulates per-channel
// sum/sumsq into bnp rows (64 x 768: [row][c]=sum, [row][384+c]=sumsq).
template<int CPAD, int COUT, int KPAD, int HI, int WI, int HP, int WP, int NBLK, int SPLIT>
__global__ __launch_bounds__(256) void conv_mfma(
    const unsigned short* __restrict__ in, const unsigned short* __restrict__ Wb,
    float* __restrict__ outf, float* __restrict__ part, float* __restrict__ bnp)
{
    constexpr int NT = NBLK / 16;
    constexpr int HI2 = HI + 2, WI2 = WI + 2;
    constexpr bool C8 = (CPAD % 8 == 0);
    constexpr int TABN = C8 ? KPAD / 8 : KPAD / 4;
    constexpr int NSTEP = KPAD / 32 / SPLIT;
    constexpr int MTOT = 2 * 16 * HP * WP * 4;

    __shared__ __align__(16) unsigned short As[64 * 40];
    __shared__ __align__(16) unsigned short Bs[NBLK * 40];
    __shared__ int tab[TABN];
    __shared__ float bs[(SPLIT == 1) ? 2 * NBLK : 1];

    const int tid = threadIdx.x;
    const int lane = tid & 63;
    const int wv = tid >> 6;
    const int blk_m = blockIdx.x;
    const int oc0 = blockIdx.y * NBLK;
    const int kc = (SPLIT > 1) ? blockIdx.z : 0;

    for (int i = tid; i < TABN; i += 256) {
        const int k = i * (C8 ? 8 : 4);
        const int s = k / CPAD, c = k % CPAD;
        tab[i] = (s < 27) ? ((((s / 9) * HI2 + (s % 9) / 3) * WI2 + (s % 3)) * CPAD + c) : -1;
    }

    const int m_l = tid & 63;
    const int oct = tid >> 6;
    const int m_g = blk_m * 64 + m_l;
    const int pooled = m_g >> 2, sub = m_g & 3;
    const int pw_g = pooled % WP;
    const int ph_g = (pooled / WP) % HP;
    const int d_g  = (pooled / (WP * HP)) & 15;
    const int b_g  = pooled / (WP * HP * 16);
    const int h_g = 2 * ph_g + (sub >> 1);
    const int w_g = 2 * pw_g + (sub & 1);
    const size_t base_m = ((((size_t)b_g * 18 + d_g) * HI2 + h_g) * WI2 + w_g) * CPAD;

    f32x4 acc[NT];
    #pragma unroll
    for (int i = 0; i < NT; ++i) acc[i] = (f32x4){0.f, 0.f, 0.f, 0.f};

    const int k_begin = kc * NSTEP * 32;
    __syncthreads();

    for (int s = 0; s < NSTEP; ++s) {
        const int k0 = k_begin + s * 32;
        if constexpr (C8) {
            const int off = tab[(k0 >> 3) + oct];
            sh8 av = (sh8){0, 0, 0, 0, 0, 0, 0, 0};
            if (off >= 0) av = *(const sh8*)(in + base_m + off);
            *(sh8*)&As[m_l * 40 + oct * 8] = av;
        } else {
            #pragma unroll
            for (int hh = 0; hh < 2; ++hh) {
                const int off = tab[(k0 >> 2) + oct * 2 + hh];
                sh4 av = (sh4){0, 0, 0, 0};
                if (off >= 0) av = *(const sh4*)(in + base_m + off);
                *(sh4*)&As[m_l * 40 + oct * 8 + hh * 4] = av;
            }
        }
        for (int i = tid; i < NBLK * 4; i += 256) {
            const int row = i >> 2, cc = i & 3;
            *(sh8*)&Bs[row * 40 + cc * 8] =
                *(const sh8*)&Wb[(size_t)(oc0 + row) * KPAD + k0 + cc * 8];
        }
        __syncthreads();
        const sh8 af = *(const sh8*)&As[(wv * 16 + (lane & 15)) * 40 + (lane >> 4) * 8];
        #pragma unroll
        for (int nt = 0; nt < NT; ++nt) {
            const sh8 bf = *(const sh8*)&Bs[(nt * 16 + (lane & 15)) * 40 + (lane >> 4) * 8];
            acc[nt] = __builtin_amdgcn_mfma_f32_16x16x32_bf16(af, bf, acc[nt], 0, 0, 0);
        }
        __syncthreads();
    }

    const int q = lane >> 4;
    const int nloc = lane & 15;
    if constexpr (SPLIT == 1) {
        for (int i = tid; i < 2 * NBLK; i += 256) bs[i] = 0.f;
        __syncthreads();
        const int pooled_o = blk_m * 16 + wv * 4 + q;
        #pragma unroll
        for (int nt = 0; nt < NT; ++nt) {
            const int oc = oc0 + nt * 16 + nloc;
            float mx = fmaxf(1.f + acc[nt][0], 0.f);
            mx = fmaxf(mx, fmaxf(1.f + acc[nt][1], 0.f));
            mx = fmaxf(mx, fmaxf(1.f + acc[nt][2], 0.f));
            mx = fmaxf(mx, fmaxf(1.f + acc[nt][3], 0.f));
            float s1 = 0.f;
            if (oc < COUT) {
                outf[(size_t)pooled_o * COUT + oc] = mx;
                s1 = mx;
            }
            float s2 = s1 * s1;
            // reduce over the wave's 4 pooled positions (lane quads)
            s1 += __shfl_xor(s1, 16);
            s1 += __shfl_xor(s1, 32);
            s2 += __shfl_xor(s2, 16);
            s2 += __shfl_xor(s2, 32);
            if (q == 0) {
                atomicAdd(&bs[nt * 16 + nloc], s1);
                atomicAdd(&bs[NBLK + nt * 16 + nloc], s2);
            }
        }
        __syncthreads();
        float* rowp = bnp + (size_t)(blk_m & 63) * 768;
        for (int i = tid; i < NBLK; i += 256) {
            const int oc = oc0 + i;
            if (oc < COUT) {
                atomicAdd(&rowp[oc], bs[i]);
                atomicAdd(&rowp[384 + oc], bs[NBLK + i]);
            }
        }
    } else {
        #pragma unroll
        for (int nt = 0; nt < NT; ++nt) {
            const int oc = oc0 + nt * 16 + nloc;
            #pragma unroll
            for (int r = 0; r < 4; ++r) {
                const int mm = blk_m * 64 + wv * 16 + q * 4 + r;
                part[((size_t)kc * MTOT + mm) * COUT + oc] = acc[nt][r];
            }
        }
    }
}

// ================= split-K reduce + clamp + pool + fused BN stats =================
template<int COUT, int HP, int WP, int SPLIT>
__global__ __launch_bounds__(256) void pool_epi(const float* __restrict__ part,
                                                float* __restrict__ outf,
                                                float* __restrict__ bnp)
{
    constexpr int PO = 2 * 16 * HP * WP;
    constexpr int M = PO * 4;
    __shared__ float bs[2 * COUT];
    const int tid = threadIdx.x;
    for (int i = tid; i < 2 * COUT; i += 256) bs[i] = 0.f;
    __syncthreads();
    const int idx = blockIdx.x * 256 + tid;
    if (idx < PO * COUT) {
        const int oc = idx % COUT;
        const int p = idx / COUT;
        float v[4] = {0.f, 0.f, 0.f, 0.f};
        for (int s = 0; s < SPLIT; ++s)
            #pragma unroll
            for (int r = 0; r < 4; ++r)
                v[r] += part[((size_t)s * M + p * 4 + r) * COUT + oc];
        float mx = fmaxf(1.f + v[0], 0.f);
        mx = fmaxf(mx, fmaxf(1.f + v[1], 0.f));
        mx = fmaxf(mx, fmaxf(1.f + v[2], 0.f));
        mx = fmaxf(mx, fmaxf(1.f + v[3], 0.f));
        outf[(size_t)p * COUT + oc] = mx;
        atomicAdd(&bs[oc], mx);
        atomicAdd(&bs[COUT + oc], mx * mx);
    }
    __syncthreads();
    float* rowp = bnp + (size_t)(blockIdx.x & 63) * 768;
    for (int i = tid; i < COUT; i += 256) {
        atomicAdd(&rowp[i], bs[i]);
        atomicAdd(&rowp[384 + i], bs[COUT + i]);
    }
}

// ================= BN reduce: sum 64 bnp rows per channel, compute st, re-zero =================
__global__ __launch_bounds__(64) void bn_reduce(float* __restrict__ bnp,
                                                const float* __restrict__ gamma,
                                                const float* __restrict__ beta,
                                                float* __restrict__ st,
                                                float inv_n)
{
    const int c = blockIdx.x, tid = threadIdx.x;
    float s = bnp[(size_t)tid * 768 + c];
    float q = bnp[(size_t)tid * 768 + 384 + c];
    bnp[(size_t)tid * 768 + c] = 0.f;
    bnp[(size_t)tid * 768 + 384 + c] = 0.f;
    #pragma unroll
    for (int off = 32; off > 0; off >>= 1) {
        s += __shfl_down(s, off);
        q += __shfl_down(q, off);
    }
    if (tid == 0) {
        const float mean = s * inv_n;
        const float var  = q * inv_n - mean * mean;
        const float sc   = gamma[c] * rsqrtf(var + EPS_BN);
        st[2 * c]     = sc;
        st[2 * c + 1] = fmaf(-mean, sc, beta[c]);
    }
}

// ================= BN apply: pre-BN fp32 flat -> bf16 halo interior =================
template<int C, int HP, int WP>
__global__ __launch_bounds__(256) void bn_apply_halo(const float* __restrict__ pre,
                                                     const float* __restrict__ st,
                                                     unsigned short* __restrict__ outh)
{
    constexpr int PO = 2 * 16 * HP * WP;
    const int idx = blockIdx.x * 256 + threadIdx.x;
    if (idx >= PO * C) return;
    const int c = idx % C;
    const int p = idx / C;
    const int pw = p % WP;
    const int ph = (p / WP) % HP;
    const int d  = (p / (WP * HP)) & 15;
    const int b  = p / (WP * HP * 16);
    const float v = fmaf(pre[idx], st[2 * c], st[2 * c + 1]);
    outh[((((size_t)b * 18 + d + 1) * (HP + 2) + ph + 1) * (WP + 2) + pw + 1) * C + c] = f2bf(v);
}

// ================= L5: flat pre-BN fp32 + BN -> NCDHW flat fp32 for fc1 =================
__global__ __launch_bounds__(256) void transpose5(const float* __restrict__ out5,
                                                  const float* __restrict__ st,
                                                  float* __restrict__ h)
{
    const int idx = blockIdx.x * 256 + threadIdx.x;
    if (idx >= 110592) return;
    const int c = idx % 384;
    const int p = idx / 384;
    const int b = p / 144;
    const int sp = p % 144;
    h[(size_t)b * 55296 + c * 144 + sp] = fmaf(out5[idx], st[2 * c], st[2 * c + 1]);
}

// ================= fc layers =================
__global__ __launch_bounds__(256) void fc1_k(const float* __restrict__ h,
                                             const float* __restrict__ w1,
                                             const float* __restrict__ b1,
                                             float* __restrict__ hout)
{
    __shared__ float r0[256];
    __shared__ float r1[256];
    const int j = blockIdx.x, tid = threadIdx.x;
    const float* wr = w1 + (size_t)j * 55296;
    float a0 = 0.f, a1 = 0.f;
    for (int k = tid * 4; k < 55296; k += 1024) {
        const float4 w = *(const float4*)(wr + k);
        const float4 u = *(const float4*)(h + k);
        const float4 v = *(const float4*)(h + 55296 + k);
        a0 += w.x * u.x + w.y * u.y + w.z * u.z + w.w * u.w;
        a1 += w.x * v.x + w.y * v.y + w.z * v.z + w.w * v.w;
    }
    r0[tid] = a0; r1[tid] = a1;
    __syncthreads();
    for (int off = 128; off > 0; off >>= 1) {
        if (tid < off) { r0[tid] += r0[tid + off]; r1[tid] += r1[tid + off]; }
        __syncthreads();
    }
    if (tid == 0) {
        hout[j]       = fmaxf(r0[0] + b1[j], 0.f);
        hout[512 + j] = fmaxf(r1[0] + b1[j], 0.f);
    }
}

__global__ __launch_bounds__(256) void fc23_k(const float* __restrict__ h1,
                                              const float* __restrict__ w2,
                                              const float* __restrict__ b2,
                                              const float* __restrict__ w3,
                                              const float* __restrict__ b3,
                                              float* __restrict__ out)
{
    __shared__ float h1s[1024];
    __shared__ float h2[512];
    const int tid = threadIdx.x;
    for (int i = tid; i < 1024; i += 256) h1s[i] = h1[i];
    __syncthreads();
    {
        const float* wr = w2 + (size_t)tid * 512;
        #pragma unroll
        for (int b = 0; b < 2; ++b) {
            float a = 0.f;
            const float* hh = h1s + b * 512;
            for (int k = 0; k < 512; ++k) a = fmaf(wr[k], hh[k], a);
            h2[b * 256 + tid] = fmaxf(a + b2[tid], 0.f);
        }
    }
    __syncthreads();
    if (tid < 101) {
        const float* wr = w3 + (size_t)tid * 256;
        #pragma unroll
        for (int b = 0; b < 2; ++b) {
            float a = 0.f;
            const float* hh = h2 + b * 256;
            for (int k = 0; k < 256; ++k) a = fmaf(wr[k], hh[k], a);
            out[b * 101 + tid] = a + b3[tid];
        }
    }
}

// ================= host =================
extern "C" void kernel_launch(void* const* d_in, const int* in_sizes, int n_in,
                              void* d_out, int out_size, void* d_ws, size_t ws_size,
                              hipStream_t stream)
{
    const float* x  = (const float*)d_in[0];
    const float* p[5], *al[5], *g[5], *q[5];
    for (int i = 0; i < 5; ++i) {
        p[i]  = (const float*)d_in[1 + 4 * i];
        al[i] = (const float*)d_in[2 + 4 * i];
        g[i]  = (const float*)d_in[3 + 4 * i];
        q[i]  = (const float*)d_in[4 + 4 * i];
    }
    const float* w1 = (const float*)d_in[21];
    const float* b1 = (const float*)d_in[22];
    const float* w2 = (const float*)d_in[23];
    const float* b2 = (const float*)d_in[24];
    const float* w3 = (const float*)d_in[25];
    const float* b3 = (const float*)d_in[26];

    float* ws = nullptr;
    hipGetSymbolAddress((void**)&ws, HIP_SYMBOL(g_ws));
    unsigned short* act = nullptr;
    hipGetSymbolAddress((void**)&act, HIP_SYMBOL(g_act));
    unsigned short* wb = nullptr;
    hipGetSymbolAddress((void**)&wb, HIP_SYMBOL(g_wb));

    float* Wf[5];
    for (int i = 0; i < 5; ++i) Wf[i] = ws + WF_OFF[i];
    float* part = ws + PART_OFF;
    float* pre  = ws + PRE_OFF;
    float* out5 = ws + OUT5_OFF;
    float* h    = ws + H_OFF;
    float* st   = ws + ST_OFF;
    float* bnp  = ws + BNP_OFF;
    float* h1   = ws + H1_OFF;

    unsigned short* xin = act + XIN_OFF;
    unsigned short* a1  = act + A1_OFF;
    unsigned short* a2  = act + A2_OFF;
    unsigned short* a3  = act + A3_OFF;
    unsigned short* a4  = act + A4_OFF;

    // zero bf16 activation halos for A1..A4 (xin fully written by convert_input)
    {
        const int n16 = (int)((AR_TOT - A1_OFF) * 2 / 16);
        zero16<<<(n16 + 255) / 256, 256, 0, stream>>>((int4*)(act + A1_OFF), n16);
    }
    convert_input<<<(2 * 18 * 114 * 114 * 4 + 255) / 256, 256, 0, stream>>>(x, xin, bnp);

    static const int KF[5] = {81, 648, 1296, 2592, 5184};
    static const int CO[5] = {24, 48, 96, 192, 384};
    static const int CP[5] = {4, 24, 48, 96, 192};
    static const int KP[5] = {128, 672, 1312, 2592, 5184};
    static const int NPAD[5] = {32, 48, 96, 192, 384};

    FuseArgs fa;
    int s0 = 0;
    for (int i = 0; i < 5; ++i) {
        fa.proj[i] = p[i]; fa.alpha[i] = al[i]; fa.Wf[i] = Wf[i];
        fa.K[i] = KF[i]; fa.CO[i] = CO[i];
        const int nt = (KF[i] + 63) / 64;
        const int mt = (CO[i] + 63) / 64;
        fa.NT[i] = nt;
        fa.start[i] = s0;
        s0 += nt * mt;
    }
    fa.start[5] = s0;
    fuse_all<<<s0, 256, 0, stream>>>(fa);

    ReordArgs ra;
    int r0 = 0;
    for (int i = 0; i < 5; ++i) {
        ra.Wf[i] = Wf[i]; ra.Wb[i] = wb + WB_OFF[i];
        ra.K[i] = KF[i]; ra.CPAD[i] = CP[i]; ra.KPAD[i] = KP[i]; ra.CO[i] = CO[i];
        ra.start[i] = r0;
        r0 += NPAD[i];
    }
    ra.start[5] = r0;
    reorder_all<<<r0, 256, 0, stream>>>(ra);

    // ---- L1 ----
    conv_mfma<4, 24, 128, 112, 112, 56, 56, 32, 1>
        <<<dim3(6272, 1), 256, 0, stream>>>(xin, wb + WB_OFF[0], pre, nullptr, bnp);
    bn_reduce<<<24, 64, 0, stream>>>(bnp, g[0], q[0], st, 1.f / 100352.f);
    bn_apply_halo<24, 56, 56><<<9408, 256, 0, stream>>>(pre, st, a1);

    // ---- L2 ----
    conv_mfma<24, 48, 672, 56, 56, 28, 28, 48, 1>
        <<<dim3(1568, 1), 256, 0, stream>>>(a1, wb + WB_OFF[1], pre, nullptr, bnp);
    bn_reduce<<<48, 64, 0, stream>>>(bnp, g[1], q[1], st, 1.f / 25088.f);
    bn_apply_halo<48, 28, 28><<<4704, 256, 0, stream>>>(pre, st, a2);

    // ---- L3 ----
    conv_mfma<48, 96, 1312, 28, 28, 14, 14, 48, 1>
        <<<dim3(392, 2), 256, 0, stream>>>(a2, wb + WB_OFF[2], pre, nullptr, bnp);
    bn_reduce<<<96, 64, 0, stream>>>(bnp, g[2], q[2], st, 1.f / 6272.f);
    bn_apply_halo<96, 14, 14><<<2352, 256, 0, stream>>>(pre, st, a3);

    // ---- L4 (split-K 3) ----
    conv_mfma<96, 192, 2592, 14, 14, 7, 7, 64, 3>
        <<<dim3(98, 3, 3), 256, 0, stream>>>(a3, wb + WB_OFF[3], nullptr, part, bnp);
    pool_epi<192, 7, 7, 3><<<1176, 256, 0, stream>>>(part, pre, bnp);
    bn_reduce<<<192, 64, 0, stream>>>(bnp, g[3], q[3], st, 1.f / 1568.f);
    bn_apply_halo<192, 7, 7><<<1176, 256, 0, stream>>>(pre, st, a4);

    // ---- L5 (split-K 6) ----
    conv_mfma<192, 384, 5184, 7, 7, 3, 3, 64, 6>
        <<<dim3(18, 6, 6), 256, 0, stream>>>(a4, wb + WB_OFF[4], nullptr, part, bnp);
    pool_epi<384, 3, 3, 6><<<432, 256, 0, stream>>>(part, out5, bnp);
    bn_reduce<<<384, 64, 0, stream>>>(bnp, g[4], q[4], st, 1.f / 288.f);

    // ---- head ----
    transpose5<<<(110592 + 255) / 256, 256, 0, stream>>>(out5, st, h);
    fc1_k<<<512, 256, 0, stream>>>(h, w1, b1, h1);
    fc23_k<<<1, 256, 0, stream>>>(h1, w2, b2, w3, b3, (float*)d_out);
}

// Round 2
// 511.497 us; speedup vs baseline: 1.0560x; 1.0560x over previous
//
#include <hip/hip_runtime.h>

#define EPS_BN 1e-5f

typedef __attribute__((ext_vector_type(8))) short sh8;
typedef __attribute__((ext_vector_type(4))) short sh4;
typedef __attribute__((ext_vector_type(4))) float f32x4;

// ================= fp32 workspace arena =================
static const size_t WF_OFF[5] = {0, 1944, 33048, 157464, 655128};  // fused fp32 weights [COUT][K]
static const size_t PART_OFF = 2645784;   // split-K partials (max 3*6272*192 = 3612672)
static const size_t PRE_OFF  = 6258456;   // pre-BN flat conv output (max 2408448)
static const size_t OUT5_OFF = 8666904;   // 110592 L5 pre-BN flat
static const size_t H_OFF    = 8777496;   // 110592 fc1 input (NCDHW flat)
static const size_t ST_OFF   = 8888088;   // 768 per-channel scale/shift
static const size_t BNP_OFF  = 8888856;   // 64 rows x 768 = 49152 bn atomic partials
static const size_t H1_OFF   = 8938008;   // 1024 fc1 output
static const size_t WS_TOT   = 8939032;   // ~35.8 MB
__device__ __align__(256) float g_ws[WS_TOT];

// bf16 activation arena (halo-padded NDHWC)
static const size_t XIN_OFF = 0;         // [2][18][114][114][4]  = 1871424 (fully written by convert_input)
static const size_t A1_OFF  = 1871424;   // [2][18][58][58][24]   = 2905344
static const size_t A2_OFF  = 4776768;   // [2][18][30][30][48]   = 1555200
static const size_t A3_OFF  = 6331968;   // [2][18][16][16][96]   = 884736
static const size_t A4_OFF  = 7216704;   // [2][18][9][9][192]    = 559872
static const size_t AR_TOT  = 7776576;
__device__ __align__(256) unsigned short g_act[AR_TOT];

// bf16 conv weights [NPAD][KPAD], k-order = s*CPAD+c
static const size_t WB_OFF[5] = {0, 4096, 36352, 162304, 659968};
__device__ __align__(256) unsigned short g_wb[2650624];

__device__ inline unsigned short f2bf(float v) {
    unsigned u = __float_as_uint(v);
    return (unsigned short)((u + 0x7fffu + ((u >> 16) & 1u)) >> 16);
}

// ================= input convert + zero A1..A4 halos + zero bnp (one dispatch) =================
__global__ __launch_bounds__(256) void init_input(const float* __restrict__ x,
                                                  unsigned short* __restrict__ xp,
                                                  float* __restrict__ bnp,
                                                  int4* __restrict__ zp, int nz)
{
    const int i = blockIdx.x * 256 + threadIdx.x;
    if (i < nz) zp[i] = make_int4(0, 0, 0, 0);
    if (i < 49152) bnp[i] = 0.f;
    if (i >= 2 * 18 * 114 * 114 * 4) return;
    const int c = i & 3;
    int t = i >> 2;
    const int xx = t % 114; t /= 114;
    const int yy = t % 114; t /= 114;
    const int zz = t % 18;
    const int b  = t / 18;
    float v = 0.f;
    if (c < 3 && (unsigned)(zz - 1) < 16u && (unsigned)(yy - 1) < 112u && (unsigned)(xx - 1) < 112u)
        v = x[(((size_t)b * 3 + c) * 16 + (zz - 1)) * 12544 + (yy - 1) * 112 + (xx - 1)];
    xp[i] = f2bf(v);
}

// ================= fuse ALL layers in one dispatch =================
struct FuseArgs {
    const float* proj[5];
    const float* alpha[5];
    float* Wf[5];
    int K[5];
    int CO[5];
    int NT[5];
    int start[6];
};

__global__ __launch_bounds__(256) void fuse_all(FuseArgs a)
{
    __shared__ __align__(16) float sa[16][64];  // [p][o]
    __shared__ __align__(16) float sp[16][64];  // [p][k]

    int l = 0;
    {
        const int bx = blockIdx.x;
        while (l < 4 && bx >= a.start[l + 1]) ++l;
    }
    const int idx = blockIdx.x - a.start[l];
    const int NT = a.NT[l];
    const int obase = (idx / NT) * 64;
    const int kbase = (idx % NT) * 64;
    const int K = a.K[l], CO = a.CO[l];
    const float* __restrict__ proj  = a.proj[l];
    const float* __restrict__ alpha = a.alpha[l];
    float* __restrict__ Wf = a.Wf[l];

    const int tid = threadIdx.x;
    const int tk = tid & 15, to = tid >> 4;

    const int pp  = tid >> 4;
    const int col = (tid & 15) * 4;
    const int o_st = obase + col;
    const int k_st = kbase + col;
    const bool a_ok  = (o_st < CO);
    const bool p_vec = ((K & 3) == 0) && (k_st + 4 <= K);

    float acc[4][4];
    #pragma unroll
    for (int i = 0; i < 4; ++i)
        #pragma unroll
        for (int j = 0; j < 4; ++j) acc[i][j] = 0.f;

    for (int p0 = 0; p0 < 512; p0 += 16) {
        const float* ap  = alpha + (size_t)(p0 + pp) * CO;
        const float* prp = proj  + (size_t)(p0 + pp) * K;
        float4 va = make_float4(0.f, 0.f, 0.f, 0.f);
        float4 vp = make_float4(0.f, 0.f, 0.f, 0.f);
        if (a_ok) va = *(const float4*)(ap + o_st);
        if (p_vec) {
            vp = *(const float4*)(prp + k_st);
        } else {
            float t4[4];
            #pragma unroll
            for (int j = 0; j < 4; ++j)
                t4[j] = (k_st + j < K) ? prp[k_st + j] : 0.f;
            vp = make_float4(t4[0], t4[1], t4[2], t4[3]);
        }
        *(float4*)&sa[pp][col] = va;
        *(float4*)&sp[pp][col] = vp;
        __syncthreads();
        #pragma unroll
        for (int p = 0; p < 16; ++p) {
            const float4 a4 = *(const float4*)&sa[p][to * 4];
            const float4 b4 = *(const float4*)&sp[p][tk * 4];
            const float aa[4] = {a4.x, a4.y, a4.z, a4.w};
            const float bb[4] = {b4.x, b4.y, b4.z, b4.w};
            #pragma unroll
            for (int i = 0; i < 4; ++i)
                #pragma unroll
                for (int j = 0; j < 4; ++j)
                    acc[i][j] = fmaf(aa[i], bb[j], acc[i][j]);
        }
        __syncthreads();
    }

    #pragma unroll
    for (int i = 0; i < 4; ++i) {
        const int o = obase + to * 4 + i;
        if (o < CO) {
            #pragma unroll
            for (int j = 0; j < 4; ++j) {
                const int kk = kbase + tk * 4 + j;
                if (kk < K) Wf[(size_t)o * K + kk] = acc[i][j];
            }
        }
    }
}

// ================= reorder ALL layers in one dispatch =================
struct ReordArgs {
    const float* Wf[5];
    unsigned short* Wb[5];
    int K[5], CPAD[5], KPAD[5], CO[5];
    int start[6];
};

__global__ __launch_bounds__(256) void reorder_all(ReordArgs a)
{
    int l = 0;
    {
        const int bx = blockIdx.x;
        while (l < 4 && bx >= a.start[l + 1]) ++l;
    }
    const int o = blockIdx.x - a.start[l];
    const int K = a.K[l], CPAD = a.CPAD[l], KPAD = a.KPAD[l], CO = a.CO[l];
    const int tid = threadIdx.x;
    unsigned short* row = a.Wb[l] + (size_t)o * KPAD;
    for (int i = tid; i < KPAD; i += 256) row[i] = 0;
    __syncthreads();
    if (o < CO) {
        const float* wr = a.Wf[l] + (size_t)o * K;
        for (int k = tid; k < K; k += 256) {
            const int c = k / 27, s = k - c * 27;
            row[s * CPAD + c] = f2bf(wr[k]);
        }
    }
}

// ================= implicit-GEMM MFMA conv + clamp(1+x,0) + pool(1,2,2) + fused BN stats =================
// 2-phase pipeline: per 32-k step, prefetch next step's global loads into regs,
// ds_read+MFMA from buf[cur], ds_write buf[cur^1], ONE barrier. Global-load
// latency hides under the current step's LDS reads + MFMA.
// BONCE (L1): whole B panel (8 KB) is LDS-resident; no per-step B staging.
template<int CPAD, int COUT, int KPAD, int HI, int WI, int HP, int WP, int NBLK, int SPLIT>
__global__ __launch_bounds__(256) void conv_mfma(
    const unsigned short* __restrict__ in, const unsigned short* __restrict__ Wb,
    float* __restrict__ outf, float* __restrict__ part, float* __restrict__ bnp)
{
    constexpr int NT = NBLK / 16;
    constexpr int HI2 = HI + 2, WI2 = WI + 2;
    constexpr bool C8 = (CPAD % 8 == 0);
    constexpr int TABN = C8 ? KPAD / 8 : KPAD / 4;
    constexpr int NSTEP = KPAD / 32 / SPLIT;
    constexpr int MTOT = 2 * 16 * HP * WP * 4;
    constexpr bool BONCE = (NBLK * KPAD * 2 <= 16384);   // L1 only
    constexpr int BROW = BONCE ? (KPAD + 8) : 40;        // B row stride (shorts)
    constexpr int BS_ELEMS = BONCE ? NBLK * BROW : 2 * NBLK * 40;

    __shared__ __align__(16) unsigned short As[2][64 * 40];
    __shared__ __align__(16) unsigned short Bs[BS_ELEMS];
    __shared__ int tab[TABN];
    __shared__ float bs[(SPLIT == 1) ? 2 * NBLK : 1];

    const int tid = threadIdx.x;
    const int lane = tid & 63;
    const int wv = tid >> 6;
    const int blk_m = blockIdx.x;
    const int oc0 = blockIdx.y * NBLK;
    const int kc = (SPLIT > 1) ? blockIdx.z : 0;

    for (int i = tid; i < TABN; i += 256) {
        const int k = i * (C8 ? 8 : 4);
        const int s = k / CPAD, c = k % CPAD;
        tab[i] = (s < 27) ? ((((s / 9) * HI2 + (s % 9) / 3) * WI2 + (s % 3)) * CPAD + c) : -1;
    }

    if constexpr (BONCE) {
        // whole B panel -> LDS once
        for (int i = tid; i < NBLK * KPAD / 8; i += 256) {
            const int r = i / (KPAD / 8), kk = i - r * (KPAD / 8);
            *(sh8*)&Bs[r * BROW + kk * 8] = *(const sh8*)&Wb[(size_t)(oc0 + r) * KPAD + kk * 8];
        }
    }

    const int m_l = tid & 63;
    const int oct = tid >> 6;
    const int m_g = blk_m * 64 + m_l;
    const int pooled = m_g >> 2, sub = m_g & 3;
    const int pw_g = pooled % WP;
    const int ph_g = (pooled / WP) % HP;
    const int d_g  = (pooled / (WP * HP)) & 15;
    const int b_g  = pooled / (WP * HP * 16);
    const int h_g = 2 * ph_g + (sub >> 1);
    const int w_g = 2 * pw_g + (sub & 1);
    const size_t base_m = ((((size_t)b_g * 18 + d_g) * HI2 + h_g) * WI2 + w_g) * CPAD;

    // B staging thread mapping (NBLK*4 <= 256 for all layers)
    const int brow = tid >> 2, bcc = tid & 3;
    const bool bload = (tid < NBLK * 4);

    f32x4 acc[NT];
    #pragma unroll
    for (int i = 0; i < NT; ++i) acc[i] = (f32x4){0.f, 0.f, 0.f, 0.f};

    const int k_begin = kc * NSTEP * 32;

    // prefetch registers
    sh8 aA; sh4 a0r, a1r; sh8 brg;

    __syncthreads();  // tab (and BONCE B) visible

    // ---- prologue: stage step 0 ----
    {
        const int k0 = k_begin;
        if constexpr (C8) {
            const int off = tab[(k0 >> 3) + oct];
            aA = (sh8){0, 0, 0, 0, 0, 0, 0, 0};
            if (off >= 0) aA = *(const sh8*)(in + base_m + off);
            *(sh8*)&As[0][m_l * 40 + oct * 8] = aA;
        } else {
            const int o0 = tab[(k0 >> 2) + oct * 2];
            const int o1 = tab[(k0 >> 2) + oct * 2 + 1];
            a0r = (sh4){0, 0, 0, 0}; a1r = (sh4){0, 0, 0, 0};
            if (o0 >= 0) a0r = *(const sh4*)(in + base_m + o0);
            if (o1 >= 0) a1r = *(const sh4*)(in + base_m + o1);
            *(sh4*)&As[0][m_l * 40 + oct * 8]     = a0r;
            *(sh4*)&As[0][m_l * 40 + oct * 8 + 4] = a1r;
        }
        if constexpr (!BONCE) {
            if (bload) {
                brg = *(const sh8*)&Wb[(size_t)(oc0 + brow) * KPAD + k0 + bcc * 8];
                *(sh8*)&Bs[0 + brow * 40 + bcc * 8] = brg;
            }
        }
    }
    __syncthreads();

    // ---- 2-phase main loop: one barrier per step ----
    int cur = 0;
    for (int s = 0; s < NSTEP; ++s) {
        const int k0 = k_begin + s * 32;
        // 1) issue next step's global loads (latency hides under MFMA below)
        if (s + 1 < NSTEP) {
            const int kn = k0 + 32;
            if constexpr (C8) {
                const int off = tab[(kn >> 3) + oct];
                aA = (sh8){0, 0, 0, 0, 0, 0, 0, 0};
                if (off >= 0) aA = *(const sh8*)(in + base_m + off);
            } else {
                const int o0 = tab[(kn >> 2) + oct * 2];
                const int o1 = tab[(kn >> 2) + oct * 2 + 1];
                a0r = (sh4){0, 0, 0, 0}; a1r = (sh4){0, 0, 0, 0};
                if (o0 >= 0) a0r = *(const sh4*)(in + base_m + o0);
                if (o1 >= 0) a1r = *(const sh4*)(in + base_m + o1);
            }
            if constexpr (!BONCE) {
                if (bload) brg = *(const sh8*)&Wb[(size_t)(oc0 + brow) * KPAD + kn + bcc * 8];
            }
        }
        // 2) compute current step from buf[cur]
        const sh8 af = *(const sh8*)&As[cur][(wv * 16 + (lane & 15)) * 40 + (lane >> 4) * 8];
        #pragma unroll
        for (int nt = 0; nt < NT; ++nt) {
            sh8 bf;
            if constexpr (BONCE)
                bf = *(const sh8*)&Bs[(nt * 16 + (lane & 15)) * BROW + k0 + (lane >> 4) * 8];
            else
                bf = *(const sh8*)&Bs[cur * NBLK * 40 + (nt * 16 + (lane & 15)) * 40 + (lane >> 4) * 8];
            acc[nt] = __builtin_amdgcn_mfma_f32_16x16x32_bf16(af, bf, acc[nt], 0, 0, 0);
        }
        // 3) write next step into buf[cur^1] (safe: our reads already consumed)
        if (s + 1 < NSTEP) {
            if constexpr (C8) {
                *(sh8*)&As[cur ^ 1][m_l * 40 + oct * 8] = aA;
            } else {
                *(sh4*)&As[cur ^ 1][m_l * 40 + oct * 8]     = a0r;
                *(sh4*)&As[cur ^ 1][m_l * 40 + oct * 8 + 4] = a1r;
            }
            if constexpr (!BONCE) {
                if (bload) *(sh8*)&Bs[(cur ^ 1) * NBLK * 40 + brow * 40 + bcc * 8] = brg;
            }
        }
        __syncthreads();
        cur ^= 1;
    }

    const int q = lane >> 4;
    const int nloc = lane & 15;
    if constexpr (SPLIT == 1) {
        for (int i = tid; i < 2 * NBLK; i += 256) bs[i] = 0.f;
        __syncthreads();
        const int pooled_o = blk_m * 16 + wv * 4 + q;
        #pragma unroll
        for (int nt = 0; nt < NT; ++nt) {
            const int oc = oc0 + nt * 16 + nloc;
            float mx = fmaxf(1.f + acc[nt][0], 0.f);
            mx = fmaxf(mx, fmaxf(1.f + acc[nt][1], 0.f));
            mx = fmaxf(mx, fmaxf(1.f + acc[nt][2], 0.f));
            mx = fmaxf(mx, fmaxf(1.f + acc[nt][3], 0.f));
            float s1 = 0.f;
            if (oc < COUT) {
                outf[(size_t)pooled_o * COUT + oc] = mx;
                s1 = mx;
            }
            float s2 = s1 * s1;
            // reduce over the wave's 4 pooled positions (lane quads)
            s1 += __shfl_xor(s1, 16);
            s1 += __shfl_xor(s1, 32);
            s2 += __shfl_xor(s2, 16);
            s2 += __shfl_xor(s2, 32);
            if (q == 0) {
                atomicAdd(&bs[nt * 16 + nloc], s1);
                atomicAdd(&bs[NBLK + nt * 16 + nloc], s2);
            }
        }
        __syncthreads();
        float* rowp = bnp + (size_t)(blk_m & 63) * 768;
        for (int i = tid; i < NBLK; i += 256) {
            const int oc = oc0 + i;
            if (oc < COUT) {
                atomicAdd(&rowp[oc], bs[i]);
                atomicAdd(&rowp[384 + oc], bs[NBLK + i]);
            }
        }
    } else {
        #pragma unroll
        for (int nt = 0; nt < NT; ++nt) {
            const int oc = oc0 + nt * 16 + nloc;
            #pragma unroll
            for (int r = 0; r < 4; ++r) {
                const int mm = blk_m * 64 + wv * 16 + q * 4 + r;
                part[((size_t)kc * MTOT + mm) * COUT + oc] = acc[nt][r];
            }
        }
    }
}

// ================= split-K reduce + clamp + pool + fused BN stats =================
template<int COUT, int HP, int WP, int SPLIT>
__global__ __launch_bounds__(256) void pool_epi(const float* __restrict__ part,
                                                float* __restrict__ outf,
                                                float* __restrict__ bnp)
{
    constexpr int PO = 2 * 16 * HP * WP;
    constexpr int M = PO * 4;
    __shared__ float bs[2 * COUT];
    const int tid = threadIdx.x;
    for (int i = tid; i < 2 * COUT; i += 256) bs[i] = 0.f;
    __syncthreads();
    const int idx = blockIdx.x * 256 + tid;
    if (idx < PO * COUT) {
        const int oc = idx % COUT;
        const int p = idx / COUT;
        float v[4] = {0.f, 0.f, 0.f, 0.f};
        for (int s = 0; s < SPLIT; ++s)
            #pragma unroll
            for (int r = 0; r < 4; ++r)
                v[r] += part[((size_t)s * M + p * 4 + r) * COUT + oc];
        float mx = fmaxf(1.f + v[0], 0.f);
        mx = fmaxf(mx, fmaxf(1.f + v[1], 0.f));
        mx = fmaxf(mx, fmaxf(1.f + v[2], 0.f));
        mx = fmaxf(mx, fmaxf(1.f + v[3], 0.f));
        outf[(size_t)p * COUT + oc] = mx;
        atomicAdd(&bs[oc], mx);
        atomicAdd(&bs[COUT + oc], mx * mx);
    }
    __syncthreads();
    float* rowp = bnp + (size_t)(blockIdx.x & 63) * 768;
    for (int i = tid; i < COUT; i += 256) {
        atomicAdd(&rowp[i], bs[i]);
        atomicAdd(&rowp[384 + i], bs[COUT + i]);
    }
}

// ================= BN reduce: sum 64 bnp rows per channel, compute st, re-zero =================
__global__ __launch_bounds__(64) void bn_reduce(float* __restrict__ bnp,
                                                const float* __restrict__ gamma,
                                                const float* __restrict__ beta,
                                                float* __restrict__ st,
                                                float inv_n)
{
    const int c = blockIdx.x, tid = threadIdx.x;
    float s = bnp[(size_t)tid * 768 + c];
    float q = bnp[(size_t)tid * 768 + 384 + c];
    bnp[(size_t)tid * 768 + c] = 0.f;
    bnp[(size_t)tid * 768 + 384 + c] = 0.f;
    #pragma unroll
    for (int off = 32; off > 0; off >>= 1) {
        s += __shfl_down(s, off);
        q += __shfl_down(q, off);
    }
    if (tid == 0) {
        const float mean = s * inv_n;
        const float var  = q * inv_n - mean * mean;
        const float sc   = gamma[c] * rsqrtf(var + EPS_BN);
        st[2 * c]     = sc;
        st[2 * c + 1] = fmaf(-mean, sc, beta[c]);
    }
}

// ================= BN apply: pre-BN fp32 flat -> bf16 halo interior =================
template<int C, int HP, int WP>
__global__ __launch_bounds__(256) void bn_apply_halo(const float* __restrict__ pre,
                                                     const float* __restrict__ st,
                                                     unsigned short* __restrict__ outh)
{
    constexpr int PO = 2 * 16 * HP * WP;
    const int idx = blockIdx.x * 256 + threadIdx.x;
    if (idx >= PO * C) return;
    const int c = idx % C;
    const int p = idx / C;
    const int pw = p % WP;
    const int ph = (p / WP) % HP;
    const int d  = (p / (WP * HP)) & 15;
    const int b  = p / (WP * HP * 16);
    const float v = fmaf(pre[idx], st[2 * c], st[2 * c + 1]);
    outh[((((size_t)b * 18 + d + 1) * (HP + 2) + ph + 1) * (WP + 2) + pw + 1) * C + c] = f2bf(v);
}

// ================= L5: flat pre-BN fp32 + BN -> NCDHW flat fp32 for fc1 =================
__global__ __launch_bounds__(256) void transpose5(const float* __restrict__ out5,
                                                  const float* __restrict__ st,
                                                  float* __restrict__ h)
{
    const int idx = blockIdx.x * 256 + threadIdx.x;
    if (idx >= 110592) return;
    const int c = idx % 384;
    const int p = idx / 384;
    const int b = p / 144;
    const int sp = p % 144;
    h[(size_t)b * 55296 + c * 144 + sp] = fmaf(out5[idx], st[2 * c], st[2 * c + 1]);
}

// ================= fc layers =================
__global__ __launch_bounds__(256) void fc1_k(const float* __restrict__ h,
                                             const float* __restrict__ w1,
                                             const float* __restrict__ b1,
                                             float* __restrict__ hout)
{
    __shared__ float r0[256];
    __shared__ float r1[256];
    const int j = blockIdx.x, tid = threadIdx.x;
    const float* wr = w1 + (size_t)j * 55296;
    float a0 = 0.f, a1 = 0.f;
    for (int k = tid * 4; k < 55296; k += 1024) {
        const float4 w = *(const float4*)(wr + k);
        const float4 u = *(const float4*)(h + k);
        const float4 v = *(const float4*)(h + 55296 + k);
        a0 += w.x * u.x + w.y * u.y + w.z * u.z + w.w * u.w;
        a1 += w.x * v.x + w.y * v.y + w.z * v.z + w.w * v.w;
    }
    r0[tid] = a0; r1[tid] = a1;
    __syncthreads();
    for (int off = 128; off > 0; off >>= 1) {
        if (tid < off) { r0[tid] += r0[tid + off]; r1[tid] += r1[tid + off]; }
        __syncthreads();
    }
    if (tid == 0) {
        hout[j]       = fmaxf(r0[0] + b1[j], 0.f);
        hout[512 + j] = fmaxf(r1[0] + b1[j], 0.f);
    }
}

__global__ __launch_bounds__(256) void fc23_k(const float* __restrict__ h1,
                                              const float* __restrict__ w2,
                                              const float* __restrict__ b2,
                                              const float* __restrict__ w3,
                                              const float* __restrict__ b3,
                                              float* __restrict__ out)
{
    __shared__ float h1s[1024];
    __shared__ float h2[512];
    const int tid = threadIdx.x;
    for (int i = tid; i < 1024; i += 256) h1s[i] = h1[i];
    __syncthreads();
    {
        const float* wr = w2 + (size_t)tid * 512;
        #pragma unroll
        for (int b = 0; b < 2; ++b) {
            float a = 0.f;
            const float* hh = h1s + b * 512;
            for (int k = 0; k < 512; ++k) a = fmaf(wr[k], hh[k], a);
            h2[b * 256 + tid] = fmaxf(a + b2[tid], 0.f);
        }
    }
    __syncthreads();
    if (tid < 101) {
        const float* wr = w3 + (size_t)tid * 256;
        #pragma unroll
        for (int b = 0; b < 2; ++b) {
            float a = 0.f;
            const float* hh = h2 + b * 256;
            for (int k = 0; k < 256; ++k) a = fmaf(wr[k], hh[k], a);
            out[b * 101 + tid] = a + b3[tid];
        }
    }
}

// ================= host =================
extern "C" void kernel_launch(void* const* d_in, const int* in_sizes, int n_in,
                              void* d_out, int out_size, void* d_ws, size_t ws_size,
                              hipStream_t stream)
{
    const float* x  = (const float*)d_in[0];
    const float* p[5], *al[5], *g[5], *q[5];
    for (int i = 0; i < 5; ++i) {
        p[i]  = (const float*)d_in[1 + 4 * i];
        al[i] = (const float*)d_in[2 + 4 * i];
        g[i]  = (const float*)d_in[3 + 4 * i];
        q[i]  = (const float*)d_in[4 + 4 * i];
    }
    const float* w1 = (const float*)d_in[21];
    const float* b1 = (const float*)d_in[22];
    const float* w2 = (const float*)d_in[23];
    const float* b2 = (const float*)d_in[24];
    const float* w3 = (const float*)d_in[25];
    const float* b3 = (const float*)d_in[26];

    float* ws = nullptr;
    hipGetSymbolAddress((void**)&ws, HIP_SYMBOL(g_ws));
    unsigned short* act = nullptr;
    hipGetSymbolAddress((void**)&act, HIP_SYMBOL(g_act));
    unsigned short* wb = nullptr;
    hipGetSymbolAddress((void**)&wb, HIP_SYMBOL(g_wb));

    float* Wf[5];
    for (int i = 0; i < 5; ++i) Wf[i] = ws + WF_OFF[i];
    float* part = ws + PART_OFF;
    float* pre  = ws + PRE_OFF;
    float* out5 = ws + OUT5_OFF;
    float* h    = ws + H_OFF;
    float* st   = ws + ST_OFF;
    float* bnp  = ws + BNP_OFF;
    float* h1   = ws + H1_OFF;

    unsigned short* xin = act + XIN_OFF;
    unsigned short* a1  = act + A1_OFF;
    unsigned short* a2  = act + A2_OFF;
    unsigned short* a3  = act + A3_OFF;
    unsigned short* a4  = act + A4_OFF;

    // convert input + zero A1..A4 halos + zero bnp, one dispatch
    {
        const int nz = (int)((AR_TOT - A1_OFF) * 2 / 16);
        init_input<<<(2 * 18 * 114 * 114 * 4 + 255) / 256, 256, 0, stream>>>(
            x, xin, bnp, (int4*)(act + A1_OFF), nz);
    }

    static const int KF[5] = {81, 648, 1296, 2592, 5184};
    static const int CO[5] = {24, 48, 96, 192, 384};
    static const int CP[5] = {4, 24, 48, 96, 192};
    static const int KP[5] = {128, 672, 1312, 2592, 5184};
    static const int NPAD[5] = {32, 48, 96, 192, 384};

    FuseArgs fa;
    int s0 = 0;
    for (int i = 0; i < 5; ++i) {
        fa.proj[i] = p[i]; fa.alpha[i] = al[i]; fa.Wf[i] = Wf[i];
        fa.K[i] = KF[i]; fa.CO[i] = CO[i];
        const int nt = (KF[i] + 63) / 64;
        const int mt = (CO[i] + 63) / 64;
        fa.NT[i] = nt;
        fa.start[i] = s0;
        s0 += nt * mt;
    }
    fa.start[5] = s0;
    fuse_all<<<s0, 256, 0, stream>>>(fa);

    ReordArgs ra;
    int r0 = 0;
    for (int i = 0; i < 5; ++i) {
        ra.Wf[i] = Wf[i]; ra.Wb[i] = wb + WB_OFF[i];
        ra.K[i] = KF[i]; ra.CPAD[i] = CP[i]; ra.KPAD[i] = KP[i]; ra.CO[i] = CO[i];
        ra.start[i] = r0;
        r0 += NPAD[i];
    }
    ra.start[5] = r0;
    reorder_all<<<r0, 256, 0, stream>>>(ra);

    // ---- L1 ----
    conv_mfma<4, 24, 128, 112, 112, 56, 56, 32, 1>
        <<<dim3(6272, 1), 256, 0, stream>>>(xin, wb + WB_OFF[0], pre, nullptr, bnp);
    bn_reduce<<<24, 64, 0, stream>>>(bnp, g[0], q[0], st, 1.f / 100352.f);
    bn_apply_halo<24, 56, 56><<<9408, 256, 0, stream>>>(pre, st, a1);

    // ---- L2 ----
    conv_mfma<24, 48, 672, 56, 56, 28, 28, 48, 1>
        <<<dim3(1568, 1), 256, 0, stream>>>(a1, wb + WB_OFF[1], pre, nullptr, bnp);
    bn_reduce<<<48, 64, 0, stream>>>(bnp, g[1], q[1], st, 1.f / 25088.f);
    bn_apply_halo<48, 28, 28><<<4704, 256, 0, stream>>>(pre, st, a2);

    // ---- L3 ----
    conv_mfma<48, 96, 1312, 28, 28, 14, 14, 48, 1>
        <<<dim3(392, 2), 256, 0, stream>>>(a2, wb + WB_OFF[2], pre, nullptr, bnp);
    bn_reduce<<<96, 64, 0, stream>>>(bnp, g[2], q[2], st, 1.f / 6272.f);
    bn_apply_halo<96, 14, 14><<<2352, 256, 0, stream>>>(pre, st, a3);

    // ---- L4 (split-K 3) ----
    conv_mfma<96, 192, 2592, 14, 14, 7, 7, 64, 3>
        <<<dim3(98, 3, 3), 256, 0, stream>>>(a3, wb + WB_OFF[3], nullptr, part, bnp);
    pool_epi<192, 7, 7, 3><<<1176, 256, 0, stream>>>(part, pre, bnp);
    bn_reduce<<<192, 64, 0, stream>>>(bnp, g[3], q[3], st, 1.f / 1568.f);
    bn_apply_halo<192, 7, 7><<<1176, 256, 0, stream>>>(pre, st, a4);

    // ---- L5 (split-K 6) ----
    conv_mfma<192, 384, 5184, 7, 7, 3, 3, 64, 6>
        <<<dim3(18, 6, 6), 256, 0, stream>>>(a4, wb + WB_OFF[4], nullptr, part, bnp);
    pool_epi<384, 3, 3, 6><<<432, 256, 0, stream>>>(part, out5, bnp);
    bn_reduce<<<384, 64, 0, stream>>>(bnp, g[4], q[4], st, 1.f / 288.f);

    // ---- head ----
    transpose5<<<(110592 + 255) / 256, 256, 0, stream>>>(out5, st, h);
    fc1_k<<<512, 256, 0, stream>>>(h, w1, b1, h1);
    fc23_k<<<1, 256, 0, stream>>>(h1, w2, b2, w3, b3, (float*)d_out);
}